// Round 6
// baseline (210.565 us; speedup 1.0000x reference)
//
#include <hip/hip_runtime.h>
#include <math.h>

// Problem constants (B=4, S=2048, H=1024, E=16, TOP_K=4)
constexpr int kTokens = 8192;   // B*S
constexpr int kH      = 1024;
constexpr int kE      = 16;
constexpr int kTopK   = 4;
constexpr int kNC     = 16;     // partial chunks = (modality, h-quarter)

// ---------------------------------------------------------------------------
// Stage 1 v6: weights in LDS (quad-broadcast reads), no scalar-cache path,
// no cross-wave reduce.
// Block = 256 thr / 4 waves = 256 tokens x one slice ks = (modality, 256-h
// quarter). Grid = 16 slices (SLOW index) x 32 token groups = 512 blocks;
// consecutive blocks share the slice -> weight global loads are L2-local.
// LDS: slice weights [256 h][16 e] = 16 KB (loaded once) + x tile
// [256 tok][36] = 36 KB -> 52 KB -> 3 blocks/CU = 12 waves/CU.
// Lane role: ln = (tq = ln>>2, eq = ln&3); lane owns tokens
// {w*64 + tq + 16i} (i=0..3) x experts [eq*4, eq*4+4) -> facc = 16 regs,
// waves own disjoint tokens (no reduce). Weight ds_read_b128 has only 4
// distinct addresses per wave (16-lane broadcast groups ~ free per G4);
// per 4-h group: 8 DS ops per 128 VALU cycles -> VALU-dense (R4/R5's limiter
// was s_load K$ round-trips: 8 s_loadx16 per 256 VALU cyc, K$ thrashed).
// Numerics = proven R1-R5 scheme: fp32 accum per 64 h (2 passes), fp64 fold,
// fp32 partial per 256-h slice, fp64 combine in stage 2.
// ---------------------------------------------------------------------------
__global__ __launch_bounds__(256, 3)
void router_fmac(const float* __restrict__ x,   const float* __restrict__ img,
                 const float* __restrict__ txt, const float* __restrict__ aud,
                 const float* __restrict__ Wg,  const float* __restrict__ Wi,
                 const float* __restrict__ Wt,  const float* __restrict__ Wa,
                 float* __restrict__ partials)
{
    __shared__ float wlds[4096];        // [256 h][16 e]  16 KB
    __shared__ float xlds[256 * 36];    // [256 tok][32 h + pad4]  36 KB

    const int t   = threadIdx.x;
    const int w   = t >> 6;             // wave 0..3
    const int ln  = t & 63;
    const int tq  = ln >> 2;            // token slot 0..15
    const int eq  = ln & 3;             // e-quad 0..3
    const int bid = blockIdx.x;
    const int ks  = bid >> 5;           // slice 0..15 (slow -> weight L2 reuse)
    const int tg  = bid & 31;           // token group 0..31
    const int m   = ks >> 2;
    const int k0  = (ks & 3) * 256;     // h offset within modality
    const int tok0 = tg * 256;

    const float* Xm = (m == 0) ? x  : (m == 1) ? img : (m == 2) ? txt : aud;
    const float* Wm = (m == 0) ? Wg : (m == 1) ? Wi  : (m == 2) ? Wt  : Wa;

    // ---- stage slice weights into LDS (16 KB, coalesced, once) ----
    {
        const float4* wsrc = (const float4*)(Wm + (size_t)k0 * kE);
#pragma unroll
        for (int i = 0; i < 4; ++i) {
            const float4 v = wsrc[t + i * 256];
            *(float4*)&wlds[(t + i * 256) * 4] = v;
        }
    }

    // ---- staging role for x: col sc (16B), rows sr+32i ----
    const int sc = t & 7;
    const int sr = t >> 3;              // 0..31
    float4 pf[8];

    // prologue: stage x pass 0
    {
        const float* src = Xm + (size_t)(tok0 + sr) * kH + k0 + sc * 4;
#pragma unroll
        for (int i = 0; i < 8; ++i)
            pf[i] = *(const float4*)(src + (size_t)(i * 32) * kH);
#pragma unroll
        for (int i = 0; i < 8; ++i)
            *(float4*)&xlds[(sr + i * 32) * 36 + sc * 4] = pf[i];
    }
    __syncthreads();

    float  facc[4][4];
    double dacc[4][4];
#pragma unroll
    for (int i = 0; i < 4; ++i)
#pragma unroll
        for (int q = 0; q < 4; ++q) dacc[i][q] = 0.0;

    const int r0 = w * 64 + tq;         // lane's token rows: r0 + 16i

    for (int p = 0; p < 8; ++p) {       // 8 passes x 32 h = 256 h
        // issue next pass's global loads (in flight during compute)
        if (p < 7) {
            const float* src = Xm + (size_t)(tok0 + sr) * kH + k0 + (p + 1) * 32 + sc * 4;
#pragma unroll
            for (int i = 0; i < 8; ++i)
                pf[i] = *(const float4*)(src + (size_t)(i * 32) * kH);
        }

        if ((p & 1) == 0) {
#pragma unroll
            for (int i = 0; i < 4; ++i)
#pragma unroll
                for (int q = 0; q < 4; ++q) facc[i][q] = 0.f;
        }

#pragma unroll
        for (int h4 = 0; h4 < 8; ++h4) {    // 4-h groups
            float4 xv[4];
#pragma unroll
            for (int i = 0; i < 4; ++i)
                xv[i] = *(const float4*)&xlds[(r0 + 16 * i) * 36 + h4 * 4];
#pragma unroll
            for (int j = 0; j < 4; ++j) {
                // 4 distinct addresses per wave (eq) -> quad-broadcast read
                const float4 wv = *(const float4*)&wlds[(p * 32 + h4 * 4 + j) * 16 + eq * 4];
#pragma unroll
                for (int i = 0; i < 4; ++i) {
                    const float xh = (j == 0) ? xv[i].x : (j == 1) ? xv[i].y
                                   : (j == 2) ? xv[i].z : xv[i].w;
                    facc[i][0] += xh * wv.x;  facc[i][1] += xh * wv.y;
                    facc[i][2] += xh * wv.z;  facc[i][3] += xh * wv.w;
                }
            }
        }

        if ((p & 1) == 1) {   // fold 64-h fp32 span into fp64
#pragma unroll
            for (int i = 0; i < 4; ++i)
#pragma unroll
                for (int q = 0; q < 4; ++q) dacc[i][q] += (double)facc[i][q];
        }

        __syncthreads();                 // all xlds reads of pass p done
        if (p < 7) {
#pragma unroll
            for (int i = 0; i < 8; ++i)
                *(float4*)&xlds[(sr + i * 32) * 36 + sc * 4] = pf[i];
        }
        __syncthreads();                 // pass p+1 tile visible
    }

    // ---- epilogue: fp32 partial [ks][tok][e]; per instr: 16 tokens x 64 B
    // contiguous (quad covers e-range) -> fully coalesced 1 KB stores ----
#pragma unroll
    for (int i = 0; i < 4; ++i) {
        const int token = tok0 + w * 64 + tq + 16 * i;
        *(float4*)&partials[((size_t)ks * kTokens + token) * kE + eq * 4] =
            make_float4((float)dacc[i][0], (float)dacc[i][1],
                        (float)dacc[i][2], (float)dacc[i][3]);
    }
}

// ---------------------------------------------------------------------------
// Stage 2: combine 16 chunk-partials + biases (fp64), softmax, top-k, output
// writes, per-block expert sums. Block = 64 tokens x 256 threads.
// ---------------------------------------------------------------------------
__global__ __launch_bounds__(256)
void router_topk(const float* __restrict__ partials,
                 const float* __restrict__ bg, const float* __restrict__ bi,
                 const float* __restrict__ bt, const float* __restrict__ ba,
                 float* __restrict__ out, float* __restrict__ blocksum)
{
    __shared__ double lgs[64][kE + 1];
    __shared__ float  pr[64][kE + 1];

    const int t    = threadIdx.x;
    const int tq   = t >> 2;      // token offset 0..63
    const int eq   = t & 3;       // e-quad
    const int tok0 = blockIdx.x * 64;

    double a0 = (double)bg[eq*4+0] + (double)bi[eq*4+0] + (double)bt[eq*4+0] + (double)ba[eq*4+0];
    double a1 = (double)bg[eq*4+1] + (double)bi[eq*4+1] + (double)bt[eq*4+1] + (double)ba[eq*4+1];
    double a2 = (double)bg[eq*4+2] + (double)bi[eq*4+2] + (double)bt[eq*4+2] + (double)ba[eq*4+2];
    double a3 = (double)bg[eq*4+3] + (double)bi[eq*4+3] + (double)bt[eq*4+3] + (double)ba[eq*4+3];

#pragma unroll
    for (int c = 0; c < kNC; ++c) {
        const float4 v = *(const float4*)(partials + ((size_t)c * kTokens + tok0 + tq) * kE + eq * 4);
        a0 += (double)v.x;  a1 += (double)v.y;  a2 += (double)v.z;  a3 += (double)v.w;
    }
    lgs[tq][eq*4+0] = a0;  lgs[tq][eq*4+1] = a1;
    lgs[tq][eq*4+2] = a2;  lgs[tq][eq*4+3] = a3;
    __syncthreads();

    if (t < 64) {
        const int tok = tok0 + t;
        double lg[kE];
#pragma unroll
        for (int e = 0; e < kE; ++e) lg[e] = lgs[t][e];

        double mx = lg[0];
#pragma unroll
        for (int e = 1; e < kE; ++e) mx = fmax(mx, lg[e]);

        float p[kE];
        float sum = 0.f;
#pragma unroll
        for (int e = 0; e < kE; ++e) {
            p[e] = expf((float)(lg[e] - mx));
            sum += p[e];
        }
        const float inv = 1.f / sum;
#pragma unroll
        for (int e = 0; e < kE; ++e) { p[e] *= inv; pr[t][e] = p[e]; }

        // top-4, descending, ties -> smallest index (matches jax.lax.top_k)
        unsigned used = 0;
        float tp[kTopK];
        int   ti[kTopK];
        float s4 = 0.f;
#pragma unroll
        for (int k = 0; k < kTopK; ++k) {
            float best = -1.f;
            int   bidx = 0;
#pragma unroll
            for (int e = 0; e < kE; ++e) {
                if (!((used >> e) & 1u) && p[e] > best) { best = p[e]; bidx = e; }
            }
            used |= 1u << bidx;
            tp[k] = best;
            ti[k] = bidx;
            s4 += best;
        }
        const float rn = 1.f / s4;

        *(float4*)&out[(size_t)tok * kTopK] =
            make_float4((float)ti[0], (float)ti[1], (float)ti[2], (float)ti[3]);
        *(float4*)&out[(size_t)kTokens * kTopK + (size_t)tok * kTopK] =
            make_float4(tp[0] * rn, tp[1] * rn, tp[2] * rn, tp[3] * rn);
    }
    __syncthreads();

    if (t < kE) {
        float s = 0.f;
#pragma unroll
        for (int tk = 0; tk < 64; ++tk) s += pr[tk][t];
        blocksum[blockIdx.x * kE + t] = s;
    }
}

// ---------------------------------------------------------------------------
// Stage 3: 128 block-partials -> mean prob per expert -> aux loss scalar
// ---------------------------------------------------------------------------
__global__ __launch_bounds__(64)
void router_aux(const float* __restrict__ blocksum, float* __restrict__ out)
{
    __shared__ double ps[kE];
    const int t = threadIdx.x;
    if (t < kE) {
        double s = 0.0;
        for (int b = 0; b < 128; ++b) s += (double)blocksum[b * kE + t];
        ps[t] = s / (double)kTokens;
    }
    __syncthreads();
    if (t == 0) {
        double aux = 0.0;
#pragma unroll
        for (int e = 0; e < kE; ++e) aux += ps[e] * log(ps[e] * (double)kE + 1e-9);
        out[(size_t)kTokens * kTopK * 2] = (float)aux;  // element 65536
    }
}

extern "C" void kernel_launch(void* const* d_in, const int* in_sizes, int n_in,
                              void* d_out, int out_size, void* d_ws, size_t ws_size,
                              hipStream_t stream)
{
    const float* x   = (const float*)d_in[0];
    const float* img = (const float*)d_in[1];
    const float* txt = (const float*)d_in[2];
    const float* aud = (const float*)d_in[3];
    const float* Wg  = (const float*)d_in[4];
    const float* bg  = (const float*)d_in[5];
    const float* Wi  = (const float*)d_in[6];
    const float* bi  = (const float*)d_in[7];
    const float* Wt  = (const float*)d_in[8];
    const float* bt  = (const float*)d_in[9];
    const float* Wa  = (const float*)d_in[10];
    const float* ba  = (const float*)d_in[11];

    float* out      = (float*)d_out;
    float* partials = (float*)d_ws;   // 16*8192*16*4 = 8 MB (ws >= 8.4 MB proven)
    float* blocksum = (float*)((char*)d_ws + (size_t)kNC * kTokens * kE * 4);  // 8 KB

    router_fmac<<<512, 256, 0, stream>>>(x, img, txt, aud, Wg, Wi, Wt, Wa, partials);
    router_topk<<<128, 256, 0, stream>>>(partials, bg, bi, bt, ba, out, blocksum);
    router_aux<<<1, 64, 0, stream>>>(blocksum, out);
}

// Round 7
// 190.810 us; speedup vs baseline: 1.1035x; 1.1035x over previous
//
#include <hip/hip_runtime.h>
#include <math.h>

// Problem constants (B=4, S=2048, H=1024, E=16, TOP_K=4)
constexpr int kTokens = 8192;   // B*S
constexpr int kH      = 1024;
constexpr int kE      = 16;
constexpr int kTopK   = 4;
constexpr int kNC     = 16;     // h-splits (64 h each)

// ---------------------------------------------------------------------------
// Stage 1 (v7 = round-4 kernel, best measured 46.7 us, with ONE change):
// hs is now the SLOW blockIdx digit. In round 4 (hs = bid & 15) co-resident
// blocks had different 16 KB weight slices -> scalar-K$ thrash -> each pass
// paid 8 x ~200cyc s_load round-trips vs 256 cyc of fmac (VALUBusy 19%).
// Now blocks 128k..128k+127 share hs: co-resident blocks issue IDENTICAL
// wave-uniform weight addresses -> K$ hits, L2-local.
//
// Everything else identical to round 4: block = 256 thr = 4 waves, 64 tokens,
// one 64-h split, 4 modality x 32-h double-buffered LDS passes (stride 36),
// wave w owns an 8-h sub-slice (weights wave-uniform -> s_load), lane = token,
// fp32 accum per 16-h, fp64 fold, cross-wave fp64 reduce via LDS, fp32
// partials[16][8192][16]. Numerics proven rounds 1-6 (absmax 9.8e-4).
// ---------------------------------------------------------------------------
__global__ __launch_bounds__(256, 5)
void router_fmac(const float* __restrict__ x,   const float* __restrict__ img,
                 const float* __restrict__ txt, const float* __restrict__ aud,
                 const float* __restrict__ Wg,  const float* __restrict__ Wi,
                 const float* __restrict__ Wt,  const float* __restrict__ Wa,
                 float* __restrict__ partials)
{
    // 20 KB: two [64][36] tile buffers; reused as red[4][64][20].
    __shared__ float smem[5120];

    const int t  = threadIdx.x;
    const int w  = __builtin_amdgcn_readfirstlane(t >> 6);  // wave id (SGPR)
    const int ln = t & 63;                                  // lane = token
    const int hs    = blockIdx.x >> 7;    // h-split 0..15  (SLOW -> K$ reuse)
    const int tg    = blockIdx.x & 127;   // token group    (fast)
    const int tok0  = tg * 64;
    const int hbase = hs * 64;

    const float* Xs[4] = { x,  img, txt, aud };
    const float* Ws[4] = { Wg, Wi,  Wt,  Wa  };

    // staging role: row sr (and sr+32), float4-col sc
    const int sc = t & 7;
    const int sr = t >> 3;   // 0..31

    // ---- prologue: stage pass 0 (modality 0, s=0) ----
    {
        const float* src = Xs[0] + (size_t)tok0 * kH + hbase + sc * 4;
        const float4 va = *(const float4*)(src + (size_t)sr * kH);
        const float4 vb = *(const float4*)(src + (size_t)(sr + 32) * kH);
        *(float4*)&smem[sr * 36 + sc * 4] = va;
        *(float4*)&smem[(sr + 32) * 36 + sc * 4] = vb;
    }
    __syncthreads();

    double dacc[kE];
#pragma unroll
    for (int e = 0; e < kE; ++e) dacc[e] = 0.0;
    float facc[kE];

#pragma unroll
    for (int p = 0; p < 8; ++p) {        // pass = (modality m = p>>1, half s = p&1)
        const int m = p >> 1;
        const int s = p & 1;

        // prefetch next pass's tile into registers (in flight during compute)
        float4 na, nb;
        if (p < 7) {
            const int m2 = (p + 1) >> 1, s2 = (p + 1) & 1;
            const float* src = Xs[m2] + (size_t)tok0 * kH + hbase + s2 * 32 + sc * 4;
            na = *(const float4*)(src + (size_t)sr * kH);
            nb = *(const float4*)(src + (size_t)(sr + 32) * kH);
        }

        if (s == 0) {
#pragma unroll
            for (int e = 0; e < kE; ++e) facc[e] = 0.f;
        }

        const float* buf   = smem + (p & 1) * 2304;
        const float* wbase = Ws[m] + (size_t)(hbase + s * 32 + w * 8) * kE; // wave-uniform

#pragma unroll
        for (int k4 = 0; k4 < 2; ++k4) {
            const float4 xv = *(const float4*)&buf[ln * 36 + w * 8 + k4 * 4];
#pragma unroll
            for (int j = 0; j < 4; ++j) {
                const float xh = (j == 0) ? xv.x : (j == 1) ? xv.y : (j == 2) ? xv.z : xv.w;
                const float* wr = wbase + (k4 * 4 + j) * kE;   // wave-uniform -> s_load
                const float4 w0 = *(const float4*)(wr + 0);
                const float4 w1 = *(const float4*)(wr + 4);
                const float4 w2 = *(const float4*)(wr + 8);
                const float4 w3 = *(const float4*)(wr + 12);
                facc[0]  += xh * w0.x;  facc[1]  += xh * w0.y;
                facc[2]  += xh * w0.z;  facc[3]  += xh * w0.w;
                facc[4]  += xh * w1.x;  facc[5]  += xh * w1.y;
                facc[6]  += xh * w1.z;  facc[7]  += xh * w1.w;
                facc[8]  += xh * w2.x;  facc[9]  += xh * w2.y;
                facc[10] += xh * w2.z;  facc[11] += xh * w2.w;
                facc[12] += xh * w3.x;  facc[13] += xh * w3.y;
                facc[14] += xh * w3.z;  facc[15] += xh * w3.w;
            }
        }

        if (s == 1) {   // fold 16-h fp32 chunk into fp64
#pragma unroll
            for (int e = 0; e < kE; ++e) dacc[e] += (double)facc[e];
        }

        // write prefetched tile into the other buffer; barrier ends the pass
        if (p < 7) {
            float* nbuf = smem + ((p + 1) & 1) * 2304;
            *(float4*)&nbuf[sr * 36 + sc * 4] = na;
            *(float4*)&nbuf[(sr + 32) * 36 + sc * 4] = nb;
        }
        __syncthreads();
    }

    // ---- cross-wave reduce: red[w][tok][e] (stride 20 floats) ----
#pragma unroll
    for (int q = 0; q < 4; ++q) {
        *(float4*)&smem[(w * 64 + ln) * 20 + q * 4] =
            make_float4((float)dacc[q * 4 + 0], (float)dacc[q * 4 + 1],
                        (float)dacc[q * 4 + 2], (float)dacc[q * 4 + 3]);
    }
    __syncthreads();
    {
        const int tok = t >> 2;
        const int eq  = t & 3;
        double s0 = 0.0, s1 = 0.0, s2 = 0.0, s3 = 0.0;
#pragma unroll
        for (int ww = 0; ww < 4; ++ww) {
            const float4 v = *(const float4*)&smem[(ww * 64 + tok) * 20 + eq * 4];
            s0 += (double)v.x;  s1 += (double)v.y;
            s2 += (double)v.z;  s3 += (double)v.w;
        }
        // coalesced float4 store of the fp32 partial [hs][tok][e]
        *(float4*)&partials[((size_t)hs * kTokens + tok0 + tok) * kE + eq * 4] =
            make_float4((float)s0, (float)s1, (float)s2, (float)s3);
    }
}

// ---------------------------------------------------------------------------
// Stage 2: combine 16 chunk-partials + biases (fp64), softmax, top-k, output
// writes, per-block expert sums. Block = 64 tokens x 256 threads.
// ---------------------------------------------------------------------------
__global__ __launch_bounds__(256)
void router_topk(const float* __restrict__ partials,
                 const float* __restrict__ bg, const float* __restrict__ bi,
                 const float* __restrict__ bt, const float* __restrict__ ba,
                 float* __restrict__ out, float* __restrict__ blocksum)
{
    __shared__ double lgs[64][kE + 1];
    __shared__ float  pr[64][kE + 1];

    const int t    = threadIdx.x;
    const int tq   = t >> 2;      // token offset 0..63
    const int eq   = t & 3;       // e-quad
    const int tok0 = blockIdx.x * 64;

    double a0 = (double)bg[eq*4+0] + (double)bi[eq*4+0] + (double)bt[eq*4+0] + (double)ba[eq*4+0];
    double a1 = (double)bg[eq*4+1] + (double)bi[eq*4+1] + (double)bt[eq*4+1] + (double)ba[eq*4+1];
    double a2 = (double)bg[eq*4+2] + (double)bi[eq*4+2] + (double)bt[eq*4+2] + (double)ba[eq*4+2];
    double a3 = (double)bg[eq*4+3] + (double)bi[eq*4+3] + (double)bt[eq*4+3] + (double)ba[eq*4+3];

#pragma unroll
    for (int c = 0; c < kNC; ++c) {
        const float4 v = *(const float4*)(partials + ((size_t)c * kTokens + tok0 + tq) * kE + eq * 4);
        a0 += (double)v.x;  a1 += (double)v.y;  a2 += (double)v.z;  a3 += (double)v.w;
    }
    lgs[tq][eq*4+0] = a0;  lgs[tq][eq*4+1] = a1;
    lgs[tq][eq*4+2] = a2;  lgs[tq][eq*4+3] = a3;
    __syncthreads();

    if (t < 64) {
        const int tok = tok0 + t;
        double lg[kE];
#pragma unroll
        for (int e = 0; e < kE; ++e) lg[e] = lgs[t][e];

        double mx = lg[0];
#pragma unroll
        for (int e = 1; e < kE; ++e) mx = fmax(mx, lg[e]);

        float p[kE];
        float sum = 0.f;
#pragma unroll
        for (int e = 0; e < kE; ++e) {
            p[e] = expf((float)(lg[e] - mx));
            sum += p[e];
        }
        const float inv = 1.f / sum;
#pragma unroll
        for (int e = 0; e < kE; ++e) { p[e] *= inv; pr[t][e] = p[e]; }

        // top-4, descending, ties -> smallest index (matches jax.lax.top_k)
        unsigned used = 0;
        float tp[kTopK];
        int   ti[kTopK];
        float s4 = 0.f;
#pragma unroll
        for (int k = 0; k < kTopK; ++k) {
            float best = -1.f;
            int   bidx = 0;
#pragma unroll
            for (int e = 0; e < kE; ++e) {
                if (!((used >> e) & 1u) && p[e] > best) { best = p[e]; bidx = e; }
            }
            used |= 1u << bidx;
            tp[k] = best;
            ti[k] = bidx;
            s4 += best;
        }
        const float rn = 1.f / s4;

        *(float4*)&out[(size_t)tok * kTopK] =
            make_float4((float)ti[0], (float)ti[1], (float)ti[2], (float)ti[3]);
        *(float4*)&out[(size_t)kTokens * kTopK + (size_t)tok * kTopK] =
            make_float4(tp[0] * rn, tp[1] * rn, tp[2] * rn, tp[3] * rn);
    }
    __syncthreads();

    if (t < kE) {
        float s = 0.f;
#pragma unroll
        for (int tk = 0; tk < 64; ++tk) s += pr[tk][t];
        blocksum[blockIdx.x * kE + t] = s;
    }
}

// ---------------------------------------------------------------------------
// Stage 3: 128 block-partials -> mean prob per expert -> aux loss scalar
// ---------------------------------------------------------------------------
__global__ __launch_bounds__(64)
void router_aux(const float* __restrict__ blocksum, float* __restrict__ out)
{
    __shared__ double ps[kE];
    const int t = threadIdx.x;
    if (t < kE) {
        double s = 0.0;
        for (int b = 0; b < 128; ++b) s += (double)blocksum[b * kE + t];
        ps[t] = s / (double)kTokens;
    }
    __syncthreads();
    if (t == 0) {
        double aux = 0.0;
#pragma unroll
        for (int e = 0; e < kE; ++e) aux += ps[e] * log(ps[e] * (double)kE + 1e-9);
        out[(size_t)kTokens * kTopK * 2] = (float)aux;  // element 65536
    }
}

extern "C" void kernel_launch(void* const* d_in, const int* in_sizes, int n_in,
                              void* d_out, int out_size, void* d_ws, size_t ws_size,
                              hipStream_t stream)
{
    const float* x   = (const float*)d_in[0];
    const float* img = (const float*)d_in[1];
    const float* txt = (const float*)d_in[2];
    const float* aud = (const float*)d_in[3];
    const float* Wg  = (const float*)d_in[4];
    const float* bg  = (const float*)d_in[5];
    const float* Wi  = (const float*)d_in[6];
    const float* bi  = (const float*)d_in[7];
    const float* Wt  = (const float*)d_in[8];
    const float* bt  = (const float*)d_in[9];
    const float* Wa  = (const float*)d_in[10];
    const float* ba  = (const float*)d_in[11];

    float* out      = (float*)d_out;
    float* partials = (float*)d_ws;   // 16*8192*16*4 = 8 MB (ws >= 8.4 MB proven)
    float* blocksum = (float*)((char*)d_ws + (size_t)kNC * kTokens * kE * 4);  // 8 KB

    router_fmac<<<2048, 256, 0, stream>>>(x, img, txt, aud, Wg, Wi, Wt, Wa, partials);
    router_topk<<<128, 256, 0, stream>>>(partials, bg, bi, bt, ba, out, blocksum);
    router_aux<<<1, 64, 0, stream>>>(blocksum, out);
}